// Round 1
// 120.600 us; speedup vs baseline: 1.0939x; 1.0939x over previous
//
#include <hip/hip_runtime.h>
#include <math.h>

#define EPS 1e-8f

__device__ __forceinline__ float wredsum(float v) {
#pragma unroll
  for (int o = 32; o > 0; o >>= 1) v += __shfl_down(v, o, 64);
  return v;  // valid in lane 0
}

// ---------------- Layer 1: [11,8192] @ [8192,512] -> 32 k-chunk partials -----
// grid (8 col-tiles of 64, 32 k-chunks of 256), block 256 = 16 colgrp x 16 ksub.
// Thread: 4 cols (float4 W1 loads), 16 k. unroll 8 -> 8 KB/wave in flight.
__global__ __launch_bounds__(256) void k_l1(const float* __restrict__ xn,
                                            const float* __restrict__ xe,
                                            const float* __restrict__ W1,
                                            float* __restrict__ p1) {
  __shared__ float red[11 * 16 * 65];  // 45760 B, stride 65 -> 2-way max (free)
  const int cg  = threadIdx.x & 15;
  const int ks  = threadIdx.x >> 4;
  const int col = blockIdx.x * 64 + cg * 4;
  const int k0  = blockIdx.y * 256 + ks * 16;

  float4 acc[11];
#pragma unroll
  for (int r = 0; r < 11; ++r) acc[r] = make_float4(0.f, 0.f, 0.f, 0.f);

#pragma unroll 8
  for (int i = 0; i < 16; ++i) {
    const int k = k0 + i;
    const float4 w = *(const float4*)&W1[(size_t)k * 512 + col];
    float xv = xn[k];
    acc[0].x = fmaf(xv, w.x, acc[0].x); acc[0].y = fmaf(xv, w.y, acc[0].y);
    acc[0].z = fmaf(xv, w.z, acc[0].z); acc[0].w = fmaf(xv, w.w, acc[0].w);
#pragma unroll
    for (int r = 0; r < 10; ++r) {
      const float xr = xe[r * 8192 + k];
      acc[r + 1].x = fmaf(xr, w.x, acc[r + 1].x);
      acc[r + 1].y = fmaf(xr, w.y, acc[r + 1].y);
      acc[r + 1].z = fmaf(xr, w.z, acc[r + 1].z);
      acc[r + 1].w = fmaf(xr, w.w, acc[r + 1].w);
    }
  }

#pragma unroll
  for (int r = 0; r < 11; ++r) {
    const int base = (r * 16 + ks) * 65 + cg * 4;
    red[base]     = acc[r].x; red[base + 1] = acc[r].y;
    red[base + 2] = acc[r].z; red[base + 3] = acc[r].w;
  }
  __syncthreads();
  if (threadIdx.x < 176) {
    const int r = threadIdx.x >> 4;
    const int c = threadIdx.x & 15;
    float4 s = make_float4(0.f, 0.f, 0.f, 0.f);
#pragma unroll
    for (int k = 0; k < 16; ++k) {
      const int b = (r * 16 + k) * 65 + c * 4;
      s.x += red[b]; s.y += red[b + 1]; s.z += red[b + 2]; s.w += red[b + 3];
    }
    *(float4*)&p1[((size_t)blockIdx.y * 11 + r) * 512 + blockIdx.x * 64 + c * 4] = s;
  }
}

// ---------------- H1 = relu(b1 + sum_ch p1): 22 blocks x 256, 1 thread/out ---
// 32 fully-unrolled stride-5632 loads -> all in flight, coalesced per chunk.
__global__ __launch_bounds__(256) void k_h1(const float* __restrict__ p1,
                                            const float* __restrict__ b1,
                                            float* __restrict__ H1) {
  const int idx = blockIdx.x * 256 + threadIdx.x;  // 22*256 = 5632 outputs
  float s = 0.f;
#pragma unroll
  for (int ch = 0; ch < 32; ++ch) s += p1[(size_t)ch * 5632 + idx];
  H1[idx] = fmaxf(s + b1[idx & 511], 0.f);
}

// ---------------- H2 = relu(H1 @ W2 + b2): 16 blocks x 256 -------------------
// Block: 16 cols. Thread (c, ks): k = kk*16+ks interleave -> LDS broadcast
// groups hit distinct banks; W2 reads coalesced per 16-lane group.
__global__ __launch_bounds__(256) void k_h2(const float* __restrict__ H1,
                                            const float* __restrict__ W2,
                                            const float* __restrict__ b2,
                                            float* __restrict__ H2) {
  __shared__ float h1s[5632];            // 22528 B
  __shared__ float red[11 * 16 * 17];    // 11968 B
  const int tid = threadIdx.x;
  for (int i = tid; i < 1408; i += 256)
    *(float4*)&h1s[i * 4] = *(const float4*)&H1[i * 4];
  __syncthreads();

  const int c = tid & 15, ks = tid >> 4;
  const int col = blockIdx.x * 16 + c;
  float acc[11];
#pragma unroll
  for (int r = 0; r < 11; ++r) acc[r] = 0.f;
#pragma unroll
  for (int kk = 0; kk < 32; ++kk) {
    const int k = kk * 16 + ks;
    const float wv = W2[(size_t)k * 256 + col];
#pragma unroll
    for (int r = 0; r < 11; ++r) acc[r] = fmaf(h1s[r * 512 + k], wv, acc[r]);
  }
#pragma unroll
  for (int r = 0; r < 11; ++r) red[(r * 16 + ks) * 17 + c] = acc[r];
  __syncthreads();
  if (tid < 176) {
    const int r = tid >> 4, cc = tid & 15;
    float s = 0.f;
#pragma unroll
    for (int k = 0; k < 16; ++k) s += red[(r * 16 + k) * 17 + cc];
    const int oc = blockIdx.x * 16 + cc;
    H2[r * 256 + oc] = fmaxf(s + b2[oc], 0.f);
  }
}

// ------- Final: enc = H2@W3 + b3, similarity, integrator. 1 block x 1024 -----
__global__ __launch_bounds__(1024) void k_fin(
    const float* __restrict__ H2, const float* __restrict__ W3,
    const float* __restrict__ b3, const float* __restrict__ mm,
    const float* __restrict__ Wi1, const float* __restrict__ bi1,
    const float* __restrict__ Wi2, const float* __restrict__ bi2,
    const float* __restrict__ Wi3, const float* __restrict__ bi3,
    float* __restrict__ out) {
  __shared__ __align__(16) float h2s[2816];    // 11264 B
  __shared__ __align__(16) float wi1s[8576];   // 34304 B
  __shared__ float red[11 * 8 * 128];          // 45056 B
  __shared__ float encs[1408];                 //  5632 B
  __shared__ float comb[134];
  __shared__ float h1s[64];
  const int t = threadIdx.x;

  // Stage H2 (704 f4) + Wi1 (2144 f4) to LDS: ~2.8 float4 per thread.
  for (int i = t; i < 2848; i += 1024) {
    if (i < 704) *(float4*)&h2s[i * 4] = *(const float4*)&H2[i * 4];
    else         *(float4*)&wi1s[(i - 704) * 4] = *(const float4*)&Wi1[(size_t)(i - 704) * 4];
  }
  __syncthreads();

  // enc partials: 8-way k-split (g), 128 cols (c). H2s reads are wave-uniform
  // broadcasts; W3 reads coalesced, read exactly once.
  {
    const int c = t & 127, g = t >> 7;
    float acc[11];
#pragma unroll
    for (int r = 0; r < 11; ++r) acc[r] = 0.f;
#pragma unroll
    for (int kk = 0; kk < 32; ++kk) {
      const int k = g * 32 + kk;
      const float wv = W3[(size_t)k * 128 + c];
#pragma unroll
      for (int r = 0; r < 11; ++r) acc[r] = fmaf(h2s[r * 256 + k], wv, acc[r]);
    }
#pragma unroll
    for (int r = 0; r < 11; ++r) red[(r * 8 + g) * 128 + c] = acc[r];
  }
  __syncthreads();
  for (int o = t; o < 1408; o += 1024) {
    const int r = o >> 7, c = o & 127;
    float s = b3[c];
#pragma unroll
    for (int g = 0; g < 8; ++g) s += red[(r * 8 + g) * 128 + c];
    encs[o] = s;  // encoder output incl. bias; row 0 = new_knowledge
  }
  __syncthreads();

  float consist = 0.f;
  float n0 = 0.f, n1 = 0.f;
  if (t < 64) {
    n0 = encs[t]; n1 = encs[64 + t];
    comb[t] = n0; comb[64 + t] = n1;
    if (t < 6) comb[128 + t] = mm[t];
  }
  __syncthreads();  // comb + wi1s ready
  if (t < 64) {
    // wave 0: similarity (runs concurrently with wave 1's MLP layer 1)
    const float nn = wredsum(n0 * n0 + n1 * n1);
#pragma unroll
    for (int r = 1; r <= 10; ++r) {
      const float e0 = encs[r * 128 + t];
      const float e1 = encs[r * 128 + 64 + t];
      const float d0 = e0 - n0, d1 = e1 - n1;
      const float g  = wredsum(d0 * d0 + d1 * d1);
      const float q  = wredsum(e0 * e0 + e1 * e1);
      const float dd = wredsum(e0 * n0 + e1 * n1);
      if (t == 0) {
        const float geo = sqrtf(g);
        const float den = fmaxf(sqrtf(nn), EPS) * fmaxf(sqrtf(q), EPS);
        consist += geo - dd / den;
      }
    }
  } else if (t < 128) {
    // wave 1: integrator layer 1
    const int tt = t - 64;
    float h = bi1[tt];
#pragma unroll 4
    for (int k = 0; k < 134; ++k) h = fmaf(comb[k], wi1s[k * 64 + tt], h);
    h1s[tt] = fmaxf(h, 0.f);
  }
  __syncthreads();
  if (t < 64) {
    float part = 0.f;
    if (t < 32) {
      float h2 = bi2[t];
#pragma unroll 8
      for (int k = 0; k < 64; ++k) h2 = fmaf(h1s[k], Wi2[k * 32 + t], h2);
      part = fmaxf(h2, 0.f) * Wi3[t];
    }
    const float qual = wredsum(part);
    if (t == 0) out[0] = consist * 0.1f + expf(-(qual + bi3[0]));
  }
}

extern "C" void kernel_launch(void* const* d_in, const int* in_sizes, int n_in,
                              void* d_out, int out_size, void* d_ws, size_t ws_size,
                              hipStream_t stream) {
  (void)in_sizes; (void)n_in; (void)out_size; (void)ws_size;
  const float* xn  = (const float*)d_in[0];
  const float* xe  = (const float*)d_in[1];
  const float* mm  = (const float*)d_in[2];
  const float* W1  = (const float*)d_in[3];
  const float* b1  = (const float*)d_in[4];
  const float* W2  = (const float*)d_in[5];
  const float* b2  = (const float*)d_in[6];
  const float* W3  = (const float*)d_in[7];
  const float* b3  = (const float*)d_in[8];
  const float* Wi1 = (const float*)d_in[9];
  const float* bi1 = (const float*)d_in[10];
  const float* Wi2 = (const float*)d_in[11];
  const float* bi2 = (const float*)d_in[12];
  const float* Wi3 = (const float*)d_in[13];
  const float* bi3 = (const float*)d_in[14];
  float* out = (float*)d_out;

  char* ws = (char*)d_ws;
  float* p1 = (float*)(ws);            // 32*11*512*4 = 720896 B
  float* H1 = (float*)(ws + 720896);   // 11*512*4    =  22528 B
  float* H2 = (float*)(ws + 743424);   // 11*256*4    =  11264 B

  hipLaunchKernelGGL(k_l1,  dim3(8, 32), dim3(256),  0, stream, xn, xe, W1, p1);
  hipLaunchKernelGGL(k_h1,  dim3(22),    dim3(256),  0, stream, p1, b1, H1);
  hipLaunchKernelGGL(k_h2,  dim3(16),    dim3(256),  0, stream, H1, W2, b2, H2);
  hipLaunchKernelGGL(k_fin, dim3(1),     dim3(1024), 0, stream,
                     H2, W3, b3, mm, Wi1, bi1, Wi2, bi2, Wi3, bi3, out);
}

// Round 3
// 120.496 us; speedup vs baseline: 1.0949x; 1.0009x over previous
//
#include <hip/hip_runtime.h>
#include <math.h>

#define EPS 1e-8f

__device__ __forceinline__ float wredsum(float v) {
#pragma unroll
  for (int o = 32; o > 0; o >>= 1) v += __shfl_down(v, o, 64);
  return v;  // valid in lane 0
}

// ---------------- Layer 1: [11,8192] @ [8192,512] -> 32 k-chunk partials -----
// grid (8 col-tiles of 64, 32 k-chunks of 256), block 256 = 16 colgrp x 16 ksub.
__global__ __launch_bounds__(256) void k_l1(const float* __restrict__ xn,
                                            const float* __restrict__ xe,
                                            const float* __restrict__ W1,
                                            float* __restrict__ p1,
                                            int* __restrict__ bars) {
  if (blockIdx.x == 0 && blockIdx.y == 0 && threadIdx.x == 0) bars[0] = 0;
  __shared__ float red[11 * 16 * 65];  // 45760 B
  const int cg  = threadIdx.x & 15;
  const int ks  = threadIdx.x >> 4;
  const int col = blockIdx.x * 64 + cg * 4;
  const int k0  = blockIdx.y * 256 + ks * 16;

  float4 acc[11];
#pragma unroll
  for (int r = 0; r < 11; ++r) acc[r] = make_float4(0.f, 0.f, 0.f, 0.f);

#pragma unroll 8
  for (int i = 0; i < 16; ++i) {
    const int k = k0 + i;
    const float4 w = *(const float4*)&W1[(size_t)k * 512 + col];
    float xv = xn[k];
    acc[0].x = fmaf(xv, w.x, acc[0].x); acc[0].y = fmaf(xv, w.y, acc[0].y);
    acc[0].z = fmaf(xv, w.z, acc[0].z); acc[0].w = fmaf(xv, w.w, acc[0].w);
#pragma unroll
    for (int r = 0; r < 10; ++r) {
      const float xr = xe[r * 8192 + k];
      acc[r + 1].x = fmaf(xr, w.x, acc[r + 1].x);
      acc[r + 1].y = fmaf(xr, w.y, acc[r + 1].y);
      acc[r + 1].z = fmaf(xr, w.z, acc[r + 1].z);
      acc[r + 1].w = fmaf(xr, w.w, acc[r + 1].w);
    }
  }

#pragma unroll
  for (int r = 0; r < 11; ++r) {
    const int base = (r * 16 + ks) * 65 + cg * 4;
    red[base]     = acc[r].x; red[base + 1] = acc[r].y;
    red[base + 2] = acc[r].z; red[base + 3] = acc[r].w;
  }
  __syncthreads();
  if (threadIdx.x < 176) {
    const int r = threadIdx.x >> 4;
    const int c = threadIdx.x & 15;
    float4 s = make_float4(0.f, 0.f, 0.f, 0.f);
#pragma unroll
    for (int k = 0; k < 16; ++k) {
      const int b = (r * 16 + k) * 65 + c * 4;
      s.x += red[b]; s.y += red[b + 1]; s.z += red[b + 2]; s.w += red[b + 3];
    }
    *(float4*)&p1[((size_t)blockIdx.y * 11 + r) * 512 + blockIdx.x * 64 + c * 4] = s;
  }
}

// ---------------- Tail: 8 blocks x 1024, last-man-standing (deadlock-free) ---
// Phase A (block j): H1 rows [64j,64j+64) = relu(b1 + sum_ch p1), then partial
// H2 contribution over that k-slice -> p2[j]. The LAST block to arrive at the
// counter (release/acquire) runs phase B: finish H2, enc = H2@W3+b3,
// similarity + integrator MLP. No spin-wait -> cannot deadlock.
__global__ __launch_bounds__(1024) void k_tail(
    const float* __restrict__ p1, const float* __restrict__ b1,
    const float* __restrict__ W2, const float* __restrict__ b2,
    const float* __restrict__ W3, const float* __restrict__ b3,
    const float* __restrict__ mm,
    const float* __restrict__ Wi1, const float* __restrict__ bi1,
    const float* __restrict__ Wi2, const float* __restrict__ bi2,
    const float* __restrict__ Wi3, const float* __restrict__ bi3,
    float* __restrict__ p2, int* __restrict__ bars, float* __restrict__ out) {
  __shared__ float h1sl[11 * 64];                 //  2816 B: H1 k-slice
  __shared__ float red[11264];                    // 45056 B: A=[4][11][256], B=[8][11][128]
  __shared__ float h2s[11 * 256];                 // 11264 B
  __shared__ __align__(16) float wi1s[134 * 64];  // 34304 B
  __shared__ float encs[1408];                    //  5632 B
  __shared__ float comb[134];
  __shared__ float h1b[64];
  __shared__ int won;
  const int t = threadIdx.x;
  const int j = blockIdx.x;

  // ---- A1: H1 slice (704 outputs; coalesced 256 B per (ch,r) row) ----
  if (t < 704) {
    const int r = t >> 6, kk = t & 63;
    const int col = j * 64 + kk;
    float s = b1[col];
#pragma unroll
    for (int ch = 0; ch < 32; ++ch) s += p1[(size_t)ch * 5632 + r * 512 + col];
    h1sl[r * 64 + kk] = fmaxf(s, 0.f);
  }
  __syncthreads();

  // ---- A2: partial H2 over k in [64j, 64j+64): 256 cols x 4 k-subslices ----
  {
    const int col = t & 255, g = t >> 8;
    float acc[11];
#pragma unroll
    for (int r = 0; r < 11; ++r) acc[r] = 0.f;
#pragma unroll
    for (int kk = 0; kk < 16; ++kk) {
      const int kl = g * 16 + kk;
      const float w = W2[(size_t)(j * 64 + kl) * 256 + col];
#pragma unroll
      for (int r = 0; r < 11; ++r) acc[r] = fmaf(h1sl[r * 64 + kl], w, acc[r]);
    }
#pragma unroll
    for (int r = 0; r < 11; ++r) red[(g * 11 + r) * 256 + col] = acc[r];
  }
  __syncthreads();
  for (int o = t; o < 2816; o += 1024) {
    const int col = o & 255, r = o >> 8;
    p2[j * 2816 + o] = red[r * 256 + col] + red[(11 + r) * 256 + col] +
                       red[(22 + r) * 256 + col] + red[(33 + r) * 256 + col];
  }

  // ---- arrival: last block wins and continues; others exit ----
  __syncthreads();  // all p2 stores issued (s_waitcnt vmcnt(0) at barrier)
  if (t == 0) {
    __threadfence();  // agent-scope release: our p2 slice visible
    const int old = __hip_atomic_fetch_add(bars, 1, __ATOMIC_ACQ_REL,
                                           __HIP_MEMORY_SCOPE_AGENT);
    won = (old == 7);
    if (won) __threadfence();  // acquire: all 8 slices now visible
  }
  __syncthreads();
  if (!won) return;

  // ---- B (winner block only) ----
  for (int i = t; i < 2144; i += 1024)  // stage Wi1 -> LDS (overlaps p2 reduce)
    *(float4*)&wi1s[i * 4] = *(const float4*)&Wi1[(size_t)i * 4];
  for (int o = t; o < 2816; o += 1024) {
    float s = b2[o & 255];
#pragma unroll
    for (int jj = 0; jj < 8; ++jj) s += p2[jj * 2816 + o];
    h2s[o] = fmaxf(s, 0.f);
  }
  __syncthreads();

  // enc partials: 128 cols x 8 k-slices of 32
  {
    const int c = t & 127, g = t >> 7;
    float acc[11];
#pragma unroll
    for (int r = 0; r < 11; ++r) acc[r] = 0.f;
#pragma unroll
    for (int kk = 0; kk < 32; ++kk) {
      const int k = g * 32 + kk;
      const float w = W3[(size_t)k * 128 + c];
#pragma unroll
      for (int r = 0; r < 11; ++r) acc[r] = fmaf(h2s[r * 256 + k], w, acc[r]);
    }
#pragma unroll
    for (int r = 0; r < 11; ++r) red[(g * 11 + r) * 128 + c] = acc[r];
  }
  __syncthreads();
  for (int o = t; o < 1408; o += 1024) {
    const int c = o & 127, r = o >> 7;
    float s = b3[c];
#pragma unroll
    for (int g = 0; g < 8; ++g) s += red[(g * 11 + r) * 128 + c];
    encs[o] = s;  // encoder outputs incl. bias; row 0 = new_knowledge
  }
  __syncthreads();

  float consist = 0.f;
  float n0 = 0.f, n1 = 0.f;
  if (t < 64) {
    n0 = encs[t]; n1 = encs[64 + t];
    comb[t] = n0; comb[64 + t] = n1;
    if (t < 6) comb[128 + t] = mm[t];
  }
  __syncthreads();  // comb + wi1s ready
  if (t < 64) {
    // wave 0: similarity (concurrent with wave 1's MLP layer 1)
    const float nn = wredsum(n0 * n0 + n1 * n1);
#pragma unroll
    for (int r = 1; r <= 10; ++r) {
      const float e0 = encs[r * 128 + t];
      const float e1 = encs[r * 128 + 64 + t];
      const float d0 = e0 - n0, d1 = e1 - n1;
      const float g  = wredsum(d0 * d0 + d1 * d1);
      const float q  = wredsum(e0 * e0 + e1 * e1);
      const float dd = wredsum(e0 * n0 + e1 * n1);
      if (t == 0) {
        const float geo = sqrtf(g);
        const float den = fmaxf(sqrtf(nn), EPS) * fmaxf(sqrtf(q), EPS);
        consist += geo - dd / den;
      }
    }
  } else if (t < 128) {
    // wave 1: integrator layer 1
    const int tt = t - 64;
    float h = bi1[tt];
#pragma unroll 4
    for (int k = 0; k < 134; ++k) h = fmaf(comb[k], wi1s[k * 64 + tt], h);
    h1b[tt] = fmaxf(h, 0.f);
  }
  __syncthreads();
  if (t < 64) {
    float part = 0.f;
    if (t < 32) {
      float h2 = bi2[t];
#pragma unroll 8
      for (int k = 0; k < 64; ++k) h2 = fmaf(h1b[k], Wi2[k * 32 + t], h2);
      part = fmaxf(h2, 0.f) * Wi3[t];
    }
    const float qual = wredsum(part);
    if (t == 0) out[0] = consist * 0.1f + expf(-(qual + bi3[0]));
  }
}

extern "C" void kernel_launch(void* const* d_in, const int* in_sizes, int n_in,
                              void* d_out, int out_size, void* d_ws, size_t ws_size,
                              hipStream_t stream) {
  (void)in_sizes; (void)n_in; (void)out_size; (void)ws_size;
  const float* xn  = (const float*)d_in[0];
  const float* xe  = (const float*)d_in[1];
  const float* mm  = (const float*)d_in[2];
  const float* W1  = (const float*)d_in[3];
  const float* b1  = (const float*)d_in[4];
  const float* W2  = (const float*)d_in[5];
  const float* b2  = (const float*)d_in[6];
  const float* W3  = (const float*)d_in[7];
  const float* b3  = (const float*)d_in[8];
  const float* Wi1 = (const float*)d_in[9];
  const float* bi1 = (const float*)d_in[10];
  const float* Wi2 = (const float*)d_in[11];
  const float* bi2 = (const float*)d_in[12];
  const float* Wi3 = (const float*)d_in[13];
  const float* bi3 = (const float*)d_in[14];
  float* out = (float*)d_out;

  char* ws = (char*)d_ws;
  float* p1   = (float*)(ws);            // 32*11*512*4 = 720896 B
  float* p2   = (float*)(ws + 720896);   // 8*11*256*4  =  90112 B
  int*   bars = (int*)  (ws + 811008);   // 4 B

  hipLaunchKernelGGL(k_l1,   dim3(8, 32), dim3(256),  0, stream, xn, xe, W1, p1, bars);
  hipLaunchKernelGGL(k_tail, dim3(8),     dim3(1024), 0, stream,
                     p1, b1, W2, b2, W3, b3, mm,
                     Wi1, bi1, Wi2, bi2, Wi3, bi3, p2, bars, out);
}

// Round 4
// 114.808 us; speedup vs baseline: 1.1491x; 1.0495x over previous
//
#include <hip/hip_runtime.h>
#include <math.h>

#define EPS 1e-8f

__device__ __forceinline__ float wredsum(float v) {
#pragma unroll
  for (int o = 32; o > 0; o >>= 1) v += __shfl_down(v, o, 64);
  return v;  // valid in lane 0
}

// 8 consecutive k-steps of a 4-col FMA: c += x[k] * w[k][0..3]
__device__ __forceinline__ void fma8(const float4* w, const float4 a,
                                     const float4 b, float4& c) {
  const float xs[8] = {a.x, a.y, a.z, a.w, b.x, b.y, b.z, b.w};
#pragma unroll
  for (int i = 0; i < 8; ++i) {
    c.x = fmaf(xs[i], w[i].x, c.x);
    c.y = fmaf(xs[i], w[i].y, c.y);
    c.z = fmaf(xs[i], w[i].z, c.z);
    c.w = fmaf(xs[i], w[i].w, c.w);
  }
}

// ---------------- Layer 1: [11,8192] @ [8192,512] -> 32 k-chunk partials -----
// grid (16 col-tiles of 32, 32 k-chunks of 256) = 512 blocks -> 2 blocks/CU,
// 2 waves/SIMD. Thread: 4 cols x 8 k; ALL loads are float4 (30 VMEM/thread,
// independent). p1 layout identical to previous round (tail kernel frozen).
__global__ __launch_bounds__(256, 2) void k_l1(const float* __restrict__ xn,
                                               const float* __restrict__ xe,
                                               const float* __restrict__ W1,
                                               float* __restrict__ p1,
                                               int* __restrict__ bars) {
  if (blockIdx.x == 0 && blockIdx.y == 0 && threadIdx.x == 0) bars[0] = 0;
  __shared__ float red[11 * 32 * 36];  // 50688 B; stride 36 keeps f4 alignment
  const int cg  = threadIdx.x & 7;     // 8 col-groups of 4 cols
  const int ks  = threadIdx.x >> 3;    // 32 k-subs of 8 k
  const int col = blockIdx.x * 32 + cg * 4;
  const int k0  = blockIdx.y * 256 + ks * 8;

  float4 w[8];
#pragma unroll
  for (int i = 0; i < 8; ++i)
    w[i] = *(const float4*)&W1[(size_t)(k0 + i) * 512 + col];

  float4 acc[11];
#pragma unroll
  for (int r = 0; r < 11; ++r) acc[r] = make_float4(0.f, 0.f, 0.f, 0.f);

  {
    const float4 a = *(const float4*)&xn[k0];
    const float4 b = *(const float4*)&xn[k0 + 4];
    fma8(w, a, b, acc[0]);
  }
#pragma unroll
  for (int r = 0; r < 10; ++r) {
    const float4 a = *(const float4*)&xe[r * 8192 + k0];
    const float4 b = *(const float4*)&xe[r * 8192 + k0 + 4];
    fma8(w, a, b, acc[r + 1]);
  }

#pragma unroll
  for (int r = 0; r < 11; ++r)
    *(float4*)&red[(r * 32 + ks) * 36 + cg * 4] = acc[r];
  __syncthreads();

  // 352 outputs (11 rows x 32 cols), 2 passes of 256/96 threads, coalesced.
  for (int o = threadIdx.x; o < 352; o += 256) {
    const int r = o >> 5, c = o & 31;
    float s = 0.f;
#pragma unroll
    for (int k = 0; k < 32; ++k) s += red[(r * 32 + k) * 36 + c];
    p1[((size_t)blockIdx.y * 11 + r) * 512 + blockIdx.x * 32 + c] = s;
  }
}

// ---------------- Tail: 8 blocks x 1024, last-man-standing (deadlock-free) ---
// UNCHANGED from previous round (frozen for clean attribution of the delta).
__global__ __launch_bounds__(1024) void k_tail(
    const float* __restrict__ p1, const float* __restrict__ b1,
    const float* __restrict__ W2, const float* __restrict__ b2,
    const float* __restrict__ W3, const float* __restrict__ b3,
    const float* __restrict__ mm,
    const float* __restrict__ Wi1, const float* __restrict__ bi1,
    const float* __restrict__ Wi2, const float* __restrict__ bi2,
    const float* __restrict__ Wi3, const float* __restrict__ bi3,
    float* __restrict__ p2, int* __restrict__ bars, float* __restrict__ out) {
  __shared__ float h1sl[11 * 64];                 //  2816 B: H1 k-slice
  __shared__ float red[11264];                    // 45056 B
  __shared__ float h2s[11 * 256];                 // 11264 B
  __shared__ __align__(16) float wi1s[134 * 64];  // 34304 B
  __shared__ float encs[1408];                    //  5632 B
  __shared__ float comb[134];
  __shared__ float h1b[64];
  __shared__ int won;
  const int t = threadIdx.x;
  const int j = blockIdx.x;

  // ---- A1: H1 slice (704 outputs; coalesced 256 B per (ch,r) row) ----
  if (t < 704) {
    const int r = t >> 6, kk = t & 63;
    const int col = j * 64 + kk;
    float s = b1[col];
#pragma unroll
    for (int ch = 0; ch < 32; ++ch) s += p1[(size_t)ch * 5632 + r * 512 + col];
    h1sl[r * 64 + kk] = fmaxf(s, 0.f);
  }
  __syncthreads();

  // ---- A2: partial H2 over k in [64j, 64j+64): 256 cols x 4 k-subslices ----
  {
    const int col = t & 255, g = t >> 8;
    float acc[11];
#pragma unroll
    for (int r = 0; r < 11; ++r) acc[r] = 0.f;
#pragma unroll
    for (int kk = 0; kk < 16; ++kk) {
      const int kl = g * 16 + kk;
      const float w = W2[(size_t)(j * 64 + kl) * 256 + col];
#pragma unroll
      for (int r = 0; r < 11; ++r) acc[r] = fmaf(h1sl[r * 64 + kl], w, acc[r]);
    }
#pragma unroll
    for (int r = 0; r < 11; ++r) red[(g * 11 + r) * 256 + col] = acc[r];
  }
  __syncthreads();
  for (int o = t; o < 2816; o += 1024) {
    const int col = o & 255, r = o >> 8;
    p2[j * 2816 + o] = red[r * 256 + col] + red[(11 + r) * 256 + col] +
                       red[(22 + r) * 256 + col] + red[(33 + r) * 256 + col];
  }

  // ---- arrival: last block wins and continues; others exit ----
  __syncthreads();  // all p2 stores issued
  if (t == 0) {
    __threadfence();  // agent-scope release: our p2 slice visible
    const int old = __hip_atomic_fetch_add(bars, 1, __ATOMIC_ACQ_REL,
                                           __HIP_MEMORY_SCOPE_AGENT);
    won = (old == 7);
    if (won) __threadfence();  // acquire: all 8 slices now visible
  }
  __syncthreads();
  if (!won) return;

  // ---- B (winner block only) ----
  for (int i = t; i < 2144; i += 1024)  // stage Wi1 -> LDS
    *(float4*)&wi1s[i * 4] = *(const float4*)&Wi1[(size_t)i * 4];
  for (int o = t; o < 2816; o += 1024) {
    float s = b2[o & 255];
#pragma unroll
    for (int jj = 0; jj < 8; ++jj) s += p2[jj * 2816 + o];
    h2s[o] = fmaxf(s, 0.f);
  }
  __syncthreads();

  // enc partials: 128 cols x 8 k-slices of 32
  {
    const int c = t & 127, g = t >> 7;
    float acc[11];
#pragma unroll
    for (int r = 0; r < 11; ++r) acc[r] = 0.f;
#pragma unroll
    for (int kk = 0; kk < 32; ++kk) {
      const int k = g * 32 + kk;
      const float w = W3[(size_t)k * 128 + c];
#pragma unroll
      for (int r = 0; r < 11; ++r) acc[r] = fmaf(h2s[r * 256 + k], w, acc[r]);
    }
#pragma unroll
    for (int r = 0; r < 11; ++r) red[(g * 11 + r) * 128 + c] = acc[r];
  }
  __syncthreads();
  for (int o = t; o < 1408; o += 1024) {
    const int c = o & 127, r = o >> 7;
    float s = b3[c];
#pragma unroll
    for (int g = 0; g < 8; ++g) s += red[(g * 11 + r) * 128 + c];
    encs[o] = s;  // encoder outputs incl. bias; row 0 = new_knowledge
  }
  __syncthreads();

  float consist = 0.f;
  float n0 = 0.f, n1 = 0.f;
  if (t < 64) {
    n0 = encs[t]; n1 = encs[64 + t];
    comb[t] = n0; comb[64 + t] = n1;
    if (t < 6) comb[128 + t] = mm[t];
  }
  __syncthreads();  // comb + wi1s ready
  if (t < 64) {
    // wave 0: similarity (concurrent with wave 1's MLP layer 1)
    const float nn = wredsum(n0 * n0 + n1 * n1);
#pragma unroll
    for (int r = 1; r <= 10; ++r) {
      const float e0 = encs[r * 128 + t];
      const float e1 = encs[r * 128 + 64 + t];
      const float d0 = e0 - n0, d1 = e1 - n1;
      const float g  = wredsum(d0 * d0 + d1 * d1);
      const float q  = wredsum(e0 * e0 + e1 * e1);
      const float dd = wredsum(e0 * n0 + e1 * n1);
      if (t == 0) {
        const float geo = sqrtf(g);
        const float den = fmaxf(sqrtf(nn), EPS) * fmaxf(sqrtf(q), EPS);
        consist += geo - dd / den;
      }
    }
  } else if (t < 128) {
    // wave 1: integrator layer 1
    const int tt = t - 64;
    float h = bi1[tt];
#pragma unroll 4
    for (int k = 0; k < 134; ++k) h = fmaf(comb[k], wi1s[k * 64 + tt], h);
    h1b[tt] = fmaxf(h, 0.f);
  }
  __syncthreads();
  if (t < 64) {
    float part = 0.f;
    if (t < 32) {
      float h2 = bi2[t];
#pragma unroll 8
      for (int k = 0; k < 64; ++k) h2 = fmaf(h1b[k], Wi2[k * 32 + t], h2);
      part = fmaxf(h2, 0.f) * Wi3[t];
    }
    const float qual = wredsum(part);
    if (t == 0) out[0] = consist * 0.1f + expf(-(qual + bi3[0]));
  }
}

extern "C" void kernel_launch(void* const* d_in, const int* in_sizes, int n_in,
                              void* d_out, int out_size, void* d_ws, size_t ws_size,
                              hipStream_t stream) {
  (void)in_sizes; (void)n_in; (void)out_size; (void)ws_size;
  const float* xn  = (const float*)d_in[0];
  const float* xe  = (const float*)d_in[1];
  const float* mm  = (const float*)d_in[2];
  const float* W1  = (const float*)d_in[3];
  const float* b1  = (const float*)d_in[4];
  const float* W2  = (const float*)d_in[5];
  const float* b2  = (const float*)d_in[6];
  const float* W3  = (const float*)d_in[7];
  const float* b3  = (const float*)d_in[8];
  const float* Wi1 = (const float*)d_in[9];
  const float* bi1 = (const float*)d_in[10];
  const float* Wi2 = (const float*)d_in[11];
  const float* bi2 = (const float*)d_in[12];
  const float* Wi3 = (const float*)d_in[13];
  const float* bi3 = (const float*)d_in[14];
  float* out = (float*)d_out;

  char* ws = (char*)d_ws;
  float* p1   = (float*)(ws);            // 32*11*512*4 = 720896 B
  float* p2   = (float*)(ws + 720896);   // 8*11*256*4  =  90112 B
  int*   bars = (int*)  (ws + 811008);   // 4 B

  hipLaunchKernelGGL(k_l1,   dim3(16, 32), dim3(256),  0, stream, xn, xe, W1, p1, bars);
  hipLaunchKernelGGL(k_tail, dim3(8),      dim3(1024), 0, stream,
                     p1, b1, W2, b2, W3, b3, mm,
                     Wi1, bi1, Wi2, bi2, Wi3, bi3, p2, bars, out);
}